// Round 11
// baseline (95.198 us; speedup 1.0000x reference)
//
#include <hip/hip_runtime.h>
#include <hip/hip_bf16.h>
#include <cstdint>
#include <cstddef>

#define TB 4
#define TC 512
#define TT 2304
#define TH 16
#define TD 32
#define TW 19
#define WOVR 9
#define EPSLN 1e-5f
#define SCALE 0.17677669529663687f   // 1/sqrt(32)
#define MTOT (TB * TT)               // 9216 rows
#define KSZ  512

typedef __attribute__((ext_vector_type(8))) short s16x8;
typedef __attribute__((ext_vector_type(8))) unsigned short u16x8;
typedef __attribute__((ext_vector_type(4))) float f32x4;

__device__ __forceinline__ float bf2f(unsigned short u) {
  union { unsigned int i; float f; } x; x.i = ((unsigned int)u) << 16; return x.f;
}
__device__ __forceinline__ unsigned short f2bf(float f) {
  union { __hip_bfloat16 h; unsigned short u; } c;
  c.h = __float2bfloat16(f);
  return c.u;
}
__device__ __forceinline__ void gload16(const void* g, void* l) {
  __builtin_amdgcn_global_load_lds(
      (const __attribute__((address_space(1))) unsigned int*)g,
      (__attribute__((address_space(3))) unsigned int*)l, 16, 0, 0);
}
__device__ __forceinline__ float mval(const unsigned char* mraw, int idx) {
  const uint32_t w0 = *(const uint32_t*)mraw;
  bool on;
  if (w0 == 1u)                 on = ((const int*)mraw)[idx] != 0;
  else if (w0 == 0x01010101u)   on = mraw[idx] != 0;
  else                          on = ((const float*)mraw)[idx] != 0.0f;
  return on ? 1.0f : 0.0f;
}

// ------- prep: mask expand + weight bf16 pack + mask tail (one kernel) -------
__global__ void k_prep(const unsigned char* __restrict__ mraw,
                       const float* __restrict__ wq, const float* __restrict__ wk,
                       const float* __restrict__ wv, const float* __restrict__ wp,
                       unsigned short* __restrict__ Wbf,
                       float* __restrict__ mf, float* __restrict__ out) {
  const int i = blockIdx.x * 256 + threadIdx.x;
  if (i < 4 * TC * TC) {
    const int z = i >> 18, r = i & (TC * TC - 1);
    const float* src = (z == 0) ? wq : (z == 1) ? wk : (z == 2) ? wv : wp;
    Wbf[i] = f2bf(src[r]);
  }
  if (i < TB * TT) {
    const float v = mval(mraw, i);
    mf[i] = v;
    out[(size_t)TB * TC * TT + i] = v;   // tuple output #2
  }
}

// ---- fused 3x (depthwise conv3 + mask + LayerNorm(C)) -> bf16 [3][B*T][C] ----
// block = 16 t's x b; 512 threads = 32 cgroups x 16 t-lanes; 16 channels each.
// Conv weights + gamma/beta staged in LDS (padded, conflict-free). All three
// taps loaded directly (independent loads, L1 absorbs overlap) - no shfl deps.
__global__ __launch_bounds__(512) void k_conv_ln_t(
    const float* __restrict__ x,
    const float* __restrict__ wq, const float* __restrict__ wk, const float* __restrict__ wv,
    const float* __restrict__ gq, const float* __restrict__ bq,
    const float* __restrict__ gk, const float* __restrict__ bk,
    const float* __restrict__ gv, const float* __restrict__ bv,
    const float* __restrict__ mf, unsigned short* __restrict__ Aall) {
  const int b = blockIdx.y;
  const int t0 = blockIdx.x * 16;
  const int tid = threadIdx.x;
  const int tt = tid & 15, cg = tid >> 4;   // cg in [0,32), 16 channels each

  __shared__ float4 wlds[3][544];           // (w0,w1,w2,-) per channel, padded
  __shared__ float2 gblds[3][544];          // (gamma,beta) per channel, padded
  __shared__ float ps[3][32][17], ps2[3][32][17];
  __shared__ float mean_s[3][16], rstd_s[3][16];

  {
    const int c = tid, cp = c + (c >> 4);
    wlds[0][cp] = make_float4(wq[c*3], wq[c*3+1], wq[c*3+2], 0.f);
    wlds[1][cp] = make_float4(wk[c*3], wk[c*3+1], wk[c*3+2], 0.f);
    wlds[2][cp] = make_float4(wv[c*3], wv[c*3+1], wv[c*3+2], 0.f);
    gblds[0][cp] = make_float2(gq[c], bq[c]);
    gblds[1][cp] = make_float2(gk[c], bk[c]);
    gblds[2][cp] = make_float2(gv[c], bv[c]);
  }
  __syncthreads();

  const int tg = t0 + tt;
  const float m = mf[b * TT + tg];
  const int tm = tg > 0 ? tg - 1 : 0;
  const int tp = tg < TT - 1 ? tg + 1 : TT - 1;
  const float zl = (tg > 0) ? 1.f : 0.f;        // zero-pad left edge
  const float zr = (tg < TT - 1) ? 1.f : 0.f;   // zero-pad right edge

  const float* xb = x + ((size_t)(b * TC + cg * 16)) * TT;
  float xm[16], x0[16], xp[16];
  #pragma unroll
  for (int i = 0; i < 16; i++) {
    const float* xc = xb + (size_t)i * TT;
    xm[i] = xc[tm]; x0[i] = xc[tg]; xp[i] = xc[tp];
  }

  float s[3] = {}, s2[3] = {};
  unsigned int yp[3][8];
  #pragma unroll
  for (int i = 0; i < 16; i++) {
    const int cp = cg * 17 + i;
    const float xml = xm[i] * zl, xpl = xp[i] * zr;
    #pragma unroll
    for (int z = 0; z < 3; z++) {
      const float4 w = wlds[z][cp];
      const float y = (w.x * xml + w.y * x0[i] + w.z * xpl) * m;
      s[z] += y; s2[z] += y * y;
      const unsigned int h = f2bf(y);
      if ((i & 1) == 0) yp[z][i >> 1] = h;
      else              yp[z][i >> 1] |= h << 16;
    }
  }
  #pragma unroll
  for (int z = 0; z < 3; z++) {
    ps[z][cg][tt] = s[z]; ps2[z][cg][tt] = s2[z];
  }
  __syncthreads();
  if (tid < 48) {
    const int z = tid >> 4, tl = tid & 15;
    float su = 0.f, su2 = 0.f;
    #pragma unroll
    for (int g = 0; g < 32; g++) { su += ps[z][g][tl]; su2 += ps2[z][g][tl]; }
    const float mean = su * (1.f / TC);
    const float var  = su2 * (1.f / TC) - mean * mean;
    mean_s[z][tl] = mean;
    rstd_s[z][tl] = rsqrtf(fmaxf(var, 0.f) + EPSLN);
  }
  __syncthreads();

  #pragma unroll
  for (int z = 0; z < 3; z++) {
    const float mean = mean_s[z][tt], rs = rstd_s[z][tt];
    unsigned short tmp[16];
    #pragma unroll
    for (int i = 0; i < 16; i++) {
      const float2 gb = gblds[z][cg * 17 + i];
      const unsigned short hb = (unsigned short)(
          (i & 1) ? (yp[z][i >> 1] >> 16) : (yp[z][i >> 1] & 0xffffu));
      tmp[i] = f2bf((bf2f(hb) - mean) * rs * gb.x + gb.y);
    }
    unsigned short* oz = Aall + ((size_t)z * MTOT + b * TT + tg) * TC + cg * 16;
    *(u16x8*)(oz)     = *(const u16x8*)(tmp);
    *(u16x8*)(oz + 8) = *(const u16x8*)(tmp + 8);
  }
}

// ---------------- MFMA GEMM: D[m][n] = sum_k A[m][k] * W[n][k] (+bias[n]) ----
// R8-proven template, pipeline deepened 3->4 buffers: stage t+3 during iter t,
// wait vmcnt(8) (tile t+1 landed, t+2/t+3 in flight). Same combined
// "s_waitcnt vmcnt(N) lgkmcnt(0); s_barrier" per K-step; buffer (t+3)&3 ==
// (t-1)&3 whose reads drained at iter t-1's lgkmcnt(0)+barrier. s_setprio
// around MFMA. Operands swapped in mfma: D lane-dim = bt rows, reg-dim = ch.
template<int F32OUT>
__global__ __launch_bounds__(256) void k_gemm_mfma(
    const unsigned short* __restrict__ Abase, const unsigned short* __restrict__ Wbase,
    const float* __restrict__ bq, const float* __restrict__ bk, const float* __restrict__ bv,
    unsigned short* __restrict__ obf, float* __restrict__ of32,
    const float* __restrict__ mf) {
  const int nw = gridDim.x;                       // multiple of 8
  int w = blockIdx.x;
  w = (w & 7) * (nw >> 3) + (w >> 3);             // chunked XCD swizzle
  const int z = w / 288;                          // 288 = 72 m-tiles * 4 n-tiles
  const int rem = w - z * 288;
  const int m0 = (rem >> 2) * 128;
  const int n0 = (rem & 3) * 128;

  const unsigned short* A = Abase + (size_t)z * MTOT * KSZ;
  const unsigned short* W = Wbase + (size_t)z * KSZ * KSZ;
  const float* bias = (z == 0) ? bq : (z == 1) ? bk : bv;

  // 4 A-buffers then 4 B-buffers, each 128x32 bf16 = 8KB; total 64KB
  __shared__ __align__(16) unsigned short smem[8 * 4096];
  const int tid = threadIdx.x;
  const int l = tid & 63, l15 = l & 15, l4 = l >> 4;
  const int wid = tid >> 6, wm = wid >> 1, wn = wid & 1;

  const int r0 = tid >> 2;
  const int c0 = (tid & 3) ^ ((r0 >> 1) & 3);
  const int r1 = r0 + 64;
  const int c1 = (tid & 3) ^ ((r1 >> 1) & 3);
  const size_t gaA0 = (size_t)(m0 + r0) * KSZ + c0 * 8;
  const size_t gaA1 = (size_t)(m0 + r1) * KSZ + c1 * 8;
  const size_t gaB0 = (size_t)(n0 + r0) * KSZ + c0 * 8;
  const size_t gaB1 = (size_t)(n0 + r1) * KSZ + c1 * 8;

  int offA[4], offB[4];
  #pragma unroll
  for (int i = 0; i < 4; i++) {
    const int ra = wm * 64 + i * 16 + l15;
    offA[i] = (ra * 4 + (l4 ^ ((ra >> 1) & 3))) * 8;
    const int rb = wn * 64 + i * 16 + l15;
    offB[i] = (rb * 4 + (l4 ^ ((rb >> 1) & 3))) * 8;
  }

  #define STAGE(buf, kk)                                           \
    do {                                                           \
      unsigned short* Ad = smem + (buf) * 4096;                    \
      unsigned short* Bd = smem + 4 * 4096 + (buf) * 4096;         \
      gload16(A + gaA0 + (kk), Ad + tid * 8);                      \
      gload16(A + gaA1 + (kk), Ad + (tid + 256) * 8);              \
      gload16(W + gaB0 + (kk), Bd + tid * 8);                      \
      gload16(W + gaB1 + (kk), Bd + (tid + 256) * 8);              \
    } while (0)

  f32x4 acc[4][4] = {};
  STAGE(0, 0);
  STAGE(1, 32);
  STAGE(2, 64);
  // tile0 landed (my 4 oldest of 12 outstanding), all threads synced
  asm volatile("s_waitcnt vmcnt(8)\ns_barrier" ::: "memory");

  #pragma unroll
  for (int t = 0; t < 16; ++t) {
    if (t + 3 < 16) STAGE((t + 3) & 3, (t + 3) * 32);
    const unsigned short* Ac = smem + (t & 3) * 4096;
    const unsigned short* Bc = smem + 4 * 4096 + (t & 3) * 4096;
    s16x8 av[4], bw[4];
    #pragma unroll
    for (int i = 0; i < 4; i++) {
      av[i] = *(const s16x8*)(Ac + offA[i]);
      bw[i] = *(const s16x8*)(Bc + offB[i]);
    }
    __builtin_amdgcn_s_setprio(1);
    #pragma unroll
    for (int mi = 0; mi < 4; mi++)
      #pragma unroll
      for (int nj = 0; nj < 4; nj++)
        acc[mi][nj] = __builtin_amdgcn_mfma_f32_16x16x32_bf16(
            bw[nj], av[mi], acc[mi][nj], 0, 0, 0);   // swapped: D reg-dim = ch
    __builtin_amdgcn_s_setprio(0);
    // lgkmcnt(0): my ds_reads done (no overwrite race); vmcnt(8): tile t+1
    // landed (t+2 and t+3's 8 loads still in flight); s_barrier: all agree.
    if (t <= 12)
      asm volatile("s_waitcnt vmcnt(8) lgkmcnt(0)\ns_barrier" ::: "memory");
    else if (t == 13)
      asm volatile("s_waitcnt vmcnt(4) lgkmcnt(0)\ns_barrier" ::: "memory");
    else if (t == 14)
      asm volatile("s_waitcnt vmcnt(0) lgkmcnt(0)\ns_barrier" ::: "memory");
  }
  #undef STAGE

  if (!F32OUT) {
    // bf16 out [bt][512]: lane holds 4 consecutive channels -> 8B packed store
    unsigned short* O = obf + (size_t)z * MTOT * KSZ;
    #pragma unroll
    for (int nj = 0; nj < 4; nj++) {
      const int ch0 = n0 + wn * 64 + nj * 16 + l4 * 4;
      const float4 bi = *(const float4*)&bias[ch0];
      #pragma unroll
      for (int mi = 0; mi < 4; mi++) {
        const int bt = m0 + wm * 64 + mi * 16 + l15;
        uint2 pk;
        pk.x = (uint32_t)f2bf(acc[mi][nj][0] + bi.x) |
               ((uint32_t)f2bf(acc[mi][nj][1] + bi.y) << 16);
        pk.y = (uint32_t)f2bf(acc[mi][nj][2] + bi.z) |
               ((uint32_t)f2bf(acc[mi][nj][3] + bi.w) << 16);
        *(uint2*)&O[(size_t)bt * KSZ + ch0] = pk;
      }
    }
  } else {
    // f32 out [B][C][T] with fused mask; lanes span 16 consecutive t
    const int bb = m0 / TT;
    const int tl0 = m0 - bb * TT;
    #pragma unroll
    for (int mi = 0; mi < 4; mi++) {
      const int bt = m0 + wm * 64 + mi * 16 + l15;
      const int tloc = tl0 + wm * 64 + mi * 16 + l15;
      const float mm = mf[bt];
      #pragma unroll
      for (int nj = 0; nj < 4; nj++) {
        const int ch0 = n0 + wn * 64 + nj * 16 + l4 * 4;
        const float4 bi = *(const float4*)&bias[ch0];
        #pragma unroll
        for (int r = 0; r < 4; r++) {
          const float biv = r == 0 ? bi.x : r == 1 ? bi.y : r == 2 ? bi.z : bi.w;
          of32[((size_t)(bb * TC + ch0 + r)) * TT + tloc] =
              (acc[mi][nj][r] + biv) * mm;
        }
      }
    }
  }
}

// ---------------- banded attention, LDS-staged K/V, d-split x2 ----------------
#define AROWS (128 + 2 * WOVR)   // 146
#define ASTR  36                 // 32 data + 4 pad ushorts = 72B rows
__global__ __launch_bounds__(256) void k_attn_lds(
    const unsigned short* __restrict__ QKV, const float* __restrict__ mf,
    unsigned short* __restrict__ AO) {
  const int t0 = blockIdx.x * 128;
  const int h = blockIdx.y, b = blockIdx.z;
  const int tid = threadIdx.x;
  const int tloc = tid >> 1, half = tid & 1;
  const size_t SZ = (size_t)MTOT * KSZ;
  const unsigned short* Qp = QKV;
  const unsigned short* Kp = QKV + SZ;
  const unsigned short* Vp = QKV + 2 * SZ;
  __shared__ unsigned short Ks[AROWS * ASTR], Vs[AROWS * ASTR];
  __shared__ float mfs[AROWS];

  for (int idx = tid; idx < 2 * AROWS * 4; idx += 256) {
    const int bufv = idx >= AROWS * 4;
    const int ci = idx - bufv * AROWS * 4;
    const int r = ci >> 2, c = ci & 3;
    const int tk = t0 - WOVR + r;
    const int tkc = tk < 0 ? 0 : (tk >= TT ? TT - 1 : tk);
    const unsigned short* src =
        (bufv ? Vp : Kp) + ((size_t)(b * TT + tkc)) * TC + h * TD + c * 8;
    uint4 v = *(const uint4*)src;
    unsigned short* dst = (bufv ? Vs : Ks) + r * ASTR + c * 8;
    uint2 lo; lo.x = v.x; lo.y = v.y;
    uint2 hi; hi.x = v.z; hi.y = v.w;
    *(uint2*)dst = lo; *(uint2*)(dst + 4) = hi;
  }
  if (tid < AROWS) {
    const int tk = t0 - WOVR + tid;
    mfs[tid] = (tk >= 0 && tk < TT) ? (mf[b * TT + tk] != 0.f ? 0.f : -1e4f)
                                    : -1e30f;
  }
  __syncthreads();

  const int t = t0 + tloc;
  const float qm = mf[b * TT + t];
  float q[16];
  {
    const unsigned short* qr = Qp + ((size_t)(b * TT + t)) * TC + h * TD + half * 16;
    #pragma unroll
    for (int c = 0; c < 2; c++) {
      u16x8 v = *(const u16x8*)(qr + c * 8);
      #pragma unroll
      for (int j = 0; j < 8; j++) q[c * 8 + j] = bf2f(v[j]);
    }
  }
  float e[TW];
  float smax = -3.0e38f;
  #pragma unroll
  for (int j = 0; j < TW; j++) {
    const unsigned short* kr = Ks + (tloc + j) * ASTR + half * 16;
    float acc = 0.f;
    #pragma unroll
    for (int c = 0; c < 4; c++) {
      uint2 w = *(const uint2*)(kr + c * 4);
      acc = fmaf(q[c*4+0], bf2f((unsigned short)(w.x & 0xffffu)), acc);
      acc = fmaf(q[c*4+1], bf2f((unsigned short)(w.x >> 16)), acc);
      acc = fmaf(q[c*4+2], bf2f((unsigned short)(w.y & 0xffffu)), acc);
      acc = fmaf(q[c*4+3], bf2f((unsigned short)(w.y >> 16)), acc);
    }
    acc += __shfl_xor(acc, 1, 64);
    const float sv = acc * SCALE + mfs[tloc + j];
    e[j] = sv;
    smax = fmaxf(smax, sv);
  }
  float den = 0.f;
  #pragma unroll
  for (int j = 0; j < TW; j++) { const float ev = __expf(e[j] - smax); e[j] = ev; den += ev; }
  float o[16] = {};
  #pragma unroll
  for (int j = 0; j < TW; j++) {
    const unsigned short* vr = Vs + (tloc + j) * ASTR + half * 16;
    const float p = e[j];
    #pragma unroll
    for (int c = 0; c < 4; c++) {
      uint2 w = *(const uint2*)(vr + c * 4);
      o[c*4+0] = fmaf(p, bf2f((unsigned short)(w.x & 0xffffu)), o[c*4+0]);
      o[c*4+1] = fmaf(p, bf2f((unsigned short)(w.x >> 16)), o[c*4+1]);
      o[c*4+2] = fmaf(p, bf2f((unsigned short)(w.y & 0xffffu)), o[c*4+2]);
      o[c*4+3] = fmaf(p, bf2f((unsigned short)(w.y >> 16)), o[c*4+3]);
    }
  }
  const float sc = qm / den;
  unsigned short tmp[16];
  #pragma unroll
  for (int i = 0; i < 16; i++) tmp[i] = f2bf(o[i] * sc);
  unsigned short* op = AO + ((size_t)(b * TT + t)) * TC + h * TD + half * 16;
  *(u16x8*)(op)     = *(const u16x8*)(tmp);
  *(u16x8*)(op + 8) = *(const u16x8*)(tmp + 8);
}

extern "C" void kernel_launch(void* const* d_in, const int* in_sizes, int n_in,
                              void* d_out, int out_size, void* d_ws, size_t ws_size,
                              hipStream_t stream) {
  const float* x       = (const float*)d_in[0];
  const float* w_qconv = (const float*)d_in[1];
  const float* w_kconv = (const float*)d_in[2];
  const float* w_vconv = (const float*)d_in[3];
  const float* g_q = (const float*)d_in[4];
  const float* b_q = (const float*)d_in[5];
  const float* g_k = (const float*)d_in[6];
  const float* b_k = (const float*)d_in[7];
  const float* g_v = (const float*)d_in[8];
  const float* b_v = (const float*)d_in[9];
  const float* w_query = (const float*)d_in[10];
  const float* b_query = (const float*)d_in[11];
  const float* w_key   = (const float*)d_in[12];
  const float* b_key   = (const float*)d_in[13];
  const float* w_value = (const float*)d_in[14];
  const float* b_value = (const float*)d_in[15];
  const float* w_proj  = (const float*)d_in[16];
  const float* b_proj  = (const float*)d_in[17];
  const unsigned char* mraw = (const unsigned char*)d_in[18];
  float* out = (float*)d_out;

  uint8_t* w8 = (uint8_t*)d_ws;
  float* mf            = (float*)w8;                                   // 36 KB
  unsigned short* Wbf  = (unsigned short*)(w8 + (1ull << 20));         // 2 MB
  unsigned short* Aall = (unsigned short*)(w8 + (4ull << 20));         // 28.3 MB
  unsigned short* QKV  = (unsigned short*)(w8 + (34ull << 20));        // 28.3 MB
  unsigned short* AO   = (unsigned short*)(w8 + (63ull << 20));        // 9.4 MB

  k_prep<<<dim3((4 * TC * TC + 255) / 256), dim3(256), 0, stream>>>(
      mraw, w_query, w_key, w_value, w_proj, Wbf, mf, out);
  k_conv_ln_t<<<dim3(TT / 16, TB), dim3(512), 0, stream>>>(
      x, w_qconv, w_kconv, w_vconv, g_q, b_q, g_k, b_k, g_v, b_v, mf, Aall);
  k_gemm_mfma<0><<<dim3(864), dim3(256), 0, stream>>>(
      Aall, Wbf, b_query, b_key, b_value, QKV, nullptr, mf);
  k_attn_lds<<<dim3(TT / 128, TH, TB), dim3(256), 0, stream>>>(QKV, mf, AO);
  k_gemm_mfma<1><<<dim3(288), dim3(256), 0, stream>>>(
      AO, Wbf + 3 * TC * TC, b_proj, b_proj, b_proj, nullptr, out, mf);
}

// Round 12
// 90.254 us; speedup vs baseline: 1.0548x; 1.0548x over previous
//
#include <hip/hip_runtime.h>
#include <hip/hip_bf16.h>
#include <cstdint>
#include <cstddef>

#define TB 4
#define TC 512
#define TT 2304
#define TH 16
#define TD 32
#define TW 19
#define WOVR 9
#define EPSLN 1e-5f
#define SCALE 0.17677669529663687f   // 1/sqrt(32)
#define MTOT (TB * TT)               // 9216 rows
#define KSZ  512

typedef __attribute__((ext_vector_type(8))) short s16x8;
typedef __attribute__((ext_vector_type(8))) unsigned short u16x8;
typedef __attribute__((ext_vector_type(4))) float f32x4;

__device__ __forceinline__ float bf2f(unsigned short u) {
  union { unsigned int i; float f; } x; x.i = ((unsigned int)u) << 16; return x.f;
}
__device__ __forceinline__ unsigned short f2bf(float f) {
  union { __hip_bfloat16 h; unsigned short u; } c;
  c.h = __float2bfloat16(f);
  return c.u;
}
__device__ __forceinline__ void gload16(const void* g, void* l) {
  __builtin_amdgcn_global_load_lds(
      (const __attribute__((address_space(1))) unsigned int*)g,
      (__attribute__((address_space(3))) unsigned int*)l, 16, 0, 0);
}
__device__ __forceinline__ float mval(const unsigned char* mraw, int idx) {
  const uint32_t w0 = *(const uint32_t*)mraw;
  bool on;
  if (w0 == 1u)                 on = ((const int*)mraw)[idx] != 0;
  else if (w0 == 0x01010101u)   on = mraw[idx] != 0;
  else                          on = ((const float*)mraw)[idx] != 0.0f;
  return on ? 1.0f : 0.0f;
}

// ---- fused: prep (weights->bf16, mask->mf+tail) + 3x (conv3+mask+LN(C)) ----
// block = 16 t's x b; 512 threads = 32 cgroups x 16 t-lanes; 16 channels each.
// Conv weights + gamma/beta staged in LDS (padded, conflict-free). All three
// taps loaded directly (independent loads, L1 absorbs overlap) - no shfl deps.
__global__ __launch_bounds__(512) void k_conv_ln_t(
    const float* __restrict__ x,
    const float* __restrict__ wq, const float* __restrict__ wk, const float* __restrict__ wv,
    const float* __restrict__ gq, const float* __restrict__ bq,
    const float* __restrict__ gk, const float* __restrict__ bk,
    const float* __restrict__ gv, const float* __restrict__ bv,
    const float* __restrict__ wquery, const float* __restrict__ wkey,
    const float* __restrict__ wvalue, const float* __restrict__ wproj,
    const unsigned char* __restrict__ mraw,
    unsigned short* __restrict__ Wbf, float* __restrict__ mf,
    float* __restrict__ outtail, unsigned short* __restrict__ Aall) {
  const int b = blockIdx.y;
  const int t0 = blockIdx.x * 16;
  const int tid = threadIdx.x;
  const int tt = tid & 15, cg = tid >> 4;   // cg in [0,32), 16 channels each

  // ---- merged prep: weight pack + mask expand (grid-strided, 576x512) ----
  {
    const int gtid = (b * 144 + blockIdx.x) * 512 + tid;   // 294912 total
    #pragma unroll
    for (int rep = 0; rep < 4; rep++) {
      const int j = gtid + rep * 294912;
      if (j < 4 * TC * TC) {
        const int zz = j >> 18, r = j & (TC * TC - 1);
        const float* src = (zz == 0) ? wquery : (zz == 1) ? wkey
                          : (zz == 2) ? wvalue : wproj;
        Wbf[j] = f2bf(src[r]);
      }
    }
    if (gtid < TB * TT) {
      const float v = mval(mraw, gtid);
      mf[gtid] = v;
      outtail[(size_t)TB * TC * TT + gtid] = v;   // tuple output #2
    }
  }

  __shared__ float4 wlds[3][544];           // (w0,w1,w2,-) per channel, padded
  __shared__ float2 gblds[3][544];          // (gamma,beta) per channel, padded
  __shared__ float ps[3][32][17], ps2[3][32][17];
  __shared__ float mean_s[3][16], rstd_s[3][16];

  {
    const int c = tid, cp = c + (c >> 4);
    wlds[0][cp] = make_float4(wq[c*3], wq[c*3+1], wq[c*3+2], 0.f);
    wlds[1][cp] = make_float4(wk[c*3], wk[c*3+1], wk[c*3+2], 0.f);
    wlds[2][cp] = make_float4(wv[c*3], wv[c*3+1], wv[c*3+2], 0.f);
    gblds[0][cp] = make_float2(gq[c], bq[c]);
    gblds[1][cp] = make_float2(gk[c], bk[c]);
    gblds[2][cp] = make_float2(gv[c], bv[c]);
  }
  __syncthreads();

  const int tg = t0 + tt;
  const float m = mval(mraw, b * TT + tg);
  const int tm = tg > 0 ? tg - 1 : 0;
  const int tp = tg < TT - 1 ? tg + 1 : TT - 1;
  const float zl = (tg > 0) ? 1.f : 0.f;        // zero-pad left edge
  const float zr = (tg < TT - 1) ? 1.f : 0.f;   // zero-pad right edge

  const float* xb = x + ((size_t)(b * TC + cg * 16)) * TT;
  float xm[16], x0[16], xp[16];
  #pragma unroll
  for (int i = 0; i < 16; i++) {
    const float* xc = xb + (size_t)i * TT;
    xm[i] = xc[tm]; x0[i] = xc[tg]; xp[i] = xc[tp];
  }

  float s[3] = {}, s2[3] = {};
  unsigned int yp[3][8];
  #pragma unroll
  for (int i = 0; i < 16; i++) {
    const int cp = cg * 17 + i;
    const float xml = xm[i] * zl, xpl = xp[i] * zr;
    #pragma unroll
    for (int z = 0; z < 3; z++) {
      const float4 w = wlds[z][cp];
      const float y = (w.x * xml + w.y * x0[i] + w.z * xpl) * m;
      s[z] += y; s2[z] += y * y;
      const unsigned int h = f2bf(y);
      if ((i & 1) == 0) yp[z][i >> 1] = h;
      else              yp[z][i >> 1] |= h << 16;
    }
  }
  #pragma unroll
  for (int z = 0; z < 3; z++) {
    ps[z][cg][tt] = s[z]; ps2[z][cg][tt] = s2[z];
  }
  __syncthreads();
  if (tid < 48) {
    const int z = tid >> 4, tl = tid & 15;
    float su = 0.f, su2 = 0.f;
    #pragma unroll
    for (int g = 0; g < 32; g++) { su += ps[z][g][tl]; su2 += ps2[z][g][tl]; }
    const float mean = su * (1.f / TC);
    const float var  = su2 * (1.f / TC) - mean * mean;
    mean_s[z][tl] = mean;
    rstd_s[z][tl] = rsqrtf(fmaxf(var, 0.f) + EPSLN);
  }
  __syncthreads();

  #pragma unroll
  for (int z = 0; z < 3; z++) {
    const float mean = mean_s[z][tt], rs = rstd_s[z][tt];
    unsigned short tmp[16];
    #pragma unroll
    for (int i = 0; i < 16; i++) {
      const float2 gb = gblds[z][cg * 17 + i];
      const unsigned short hb = (unsigned short)(
          (i & 1) ? (yp[z][i >> 1] >> 16) : (yp[z][i >> 1] & 0xffffu));
      tmp[i] = f2bf((bf2f(hb) - mean) * rs * gb.x + gb.y);
    }
    unsigned short* oz = Aall + ((size_t)z * MTOT + b * TT + tg) * TC + cg * 16;
    *(u16x8*)(oz)     = *(const u16x8*)(tmp);
    *(u16x8*)(oz + 8) = *(const u16x8*)(tmp + 8);
  }
}

// ---------------- MFMA GEMM: D[m][n] = sum_k A[m][k] * W[n][k] (+bias[n]) ----
// PROVEN R10 schedule (byte-identical): 128x128 tile, 4 waves (2x2), 3-stage
// LDS pipeline, counted vmcnt; ONE combined "s_waitcnt vmcnt(N) lgkmcnt(0);
// s_barrier" per K-step. s_setprio around MFMA cluster. Operands swapped in
// mfma so D lane-dim = bt rows, reg-dim = channels.
template<int F32OUT>
__global__ __launch_bounds__(256) void k_gemm_mfma(
    const unsigned short* __restrict__ Abase, const unsigned short* __restrict__ Wbase,
    const float* __restrict__ bq, const float* __restrict__ bk, const float* __restrict__ bv,
    unsigned short* __restrict__ obf, float* __restrict__ of32,
    const float* __restrict__ mf) {
  const int nw = gridDim.x;                       // multiple of 8
  int w = blockIdx.x;
  w = (w & 7) * (nw >> 3) + (w >> 3);             // chunked XCD swizzle
  const int z = w / 288;                          // 288 = 72 m-tiles * 4 n-tiles
  const int rem = w - z * 288;
  const int m0 = (rem >> 2) * 128;
  const int n0 = (rem & 3) * 128;

  const unsigned short* A = Abase + (size_t)z * MTOT * KSZ;
  const unsigned short* W = Wbase + (size_t)z * KSZ * KSZ;
  const float* bias = (z == 0) ? bq : (z == 1) ? bk : bv;

  // 3 A-buffers then 3 B-buffers, each 128x32 bf16 = 8KB; total 48KB
  __shared__ __align__(16) unsigned short smem[6 * 4096];
  const int tid = threadIdx.x;
  const int l = tid & 63, l15 = l & 15, l4 = l >> 4;
  const int wid = tid >> 6, wm = wid >> 1, wn = wid & 1;

  const int r0 = tid >> 2;
  const int c0 = (tid & 3) ^ ((r0 >> 1) & 3);
  const int r1 = r0 + 64;
  const int c1 = (tid & 3) ^ ((r1 >> 1) & 3);
  const size_t gaA0 = (size_t)(m0 + r0) * KSZ + c0 * 8;
  const size_t gaA1 = (size_t)(m0 + r1) * KSZ + c1 * 8;
  const size_t gaB0 = (size_t)(n0 + r0) * KSZ + c0 * 8;
  const size_t gaB1 = (size_t)(n0 + r1) * KSZ + c1 * 8;

  int offA[4], offB[4];
  #pragma unroll
  for (int i = 0; i < 4; i++) {
    const int ra = wm * 64 + i * 16 + l15;
    offA[i] = (ra * 4 + (l4 ^ ((ra >> 1) & 3))) * 8;
    const int rb = wn * 64 + i * 16 + l15;
    offB[i] = (rb * 4 + (l4 ^ ((rb >> 1) & 3))) * 8;
  }

  #define STAGE(buf, kk)                                           \
    do {                                                           \
      unsigned short* Ad = smem + (buf) * 4096;                    \
      unsigned short* Bd = smem + 3 * 4096 + (buf) * 4096;         \
      gload16(A + gaA0 + (kk), Ad + tid * 8);                      \
      gload16(A + gaA1 + (kk), Ad + (tid + 256) * 8);              \
      gload16(W + gaB0 + (kk), Bd + tid * 8);                      \
      gload16(W + gaB1 + (kk), Bd + (tid + 256) * 8);              \
    } while (0)

  f32x4 acc[4][4] = {};
  STAGE(0, 0);
  STAGE(1, 32);
  // tile0 landed (my 4 oldest of 8 outstanding), all threads synced
  asm volatile("s_waitcnt vmcnt(4)\ns_barrier" ::: "memory");

  #pragma unroll
  for (int t = 0; t < 16; ++t) {
    if (t + 2 < 16) STAGE((t + 2) % 3, (t + 2) * 32);
    const unsigned short* Ac = smem + (t % 3) * 4096;
    const unsigned short* Bc = smem + 3 * 4096 + (t % 3) * 4096;
    s16x8 av[4], bw[4];
    #pragma unroll
    for (int i = 0; i < 4; i++) {
      av[i] = *(const s16x8*)(Ac + offA[i]);
      bw[i] = *(const s16x8*)(Bc + offB[i]);
    }
    __builtin_amdgcn_s_setprio(1);
    #pragma unroll
    for (int mi = 0; mi < 4; mi++)
      #pragma unroll
      for (int nj = 0; nj < 4; nj++)
        acc[mi][nj] = __builtin_amdgcn_mfma_f32_16x16x32_bf16(
            bw[nj], av[mi], acc[mi][nj], 0, 0, 0);   // swapped: D reg-dim = ch
    __builtin_amdgcn_s_setprio(0);
    // lgkmcnt(0): my ds_reads done (no overwrite race); vmcnt(4): tile t+1
    // landed (4 loads for t+2 still in flight); s_barrier: all threads agree.
    if (t < 14)
      asm volatile("s_waitcnt vmcnt(4) lgkmcnt(0)\ns_barrier" ::: "memory");
    else if (t == 14)
      asm volatile("s_waitcnt vmcnt(0) lgkmcnt(0)\ns_barrier" ::: "memory");
  }
  #undef STAGE

  if (!F32OUT) {
    // bf16 out [bt][512]: lane holds 4 consecutive channels -> 8B packed store
    unsigned short* O = obf + (size_t)z * MTOT * KSZ;
    #pragma unroll
    for (int nj = 0; nj < 4; nj++) {
      const int ch0 = n0 + wn * 64 + nj * 16 + l4 * 4;
      const float4 bi = *(const float4*)&bias[ch0];
      #pragma unroll
      for (int mi = 0; mi < 4; mi++) {
        const int bt = m0 + wm * 64 + mi * 16 + l15;
        uint2 pk;
        pk.x = (uint32_t)f2bf(acc[mi][nj][0] + bi.x) |
               ((uint32_t)f2bf(acc[mi][nj][1] + bi.y) << 16);
        pk.y = (uint32_t)f2bf(acc[mi][nj][2] + bi.z) |
               ((uint32_t)f2bf(acc[mi][nj][3] + bi.w) << 16);
        *(uint2*)&O[(size_t)bt * KSZ + ch0] = pk;
      }
    }
  } else {
    // f32 out [B][C][T] with fused mask; lanes span 16 consecutive t
    const int bb = m0 / TT;
    const int tl0 = m0 - bb * TT;
    #pragma unroll
    for (int mi = 0; mi < 4; mi++) {
      const int bt = m0 + wm * 64 + mi * 16 + l15;
      const int tloc = tl0 + wm * 64 + mi * 16 + l15;
      const float mm = mf[bt];
      #pragma unroll
      for (int nj = 0; nj < 4; nj++) {
        const int ch0 = n0 + wn * 64 + nj * 16 + l4 * 4;
        const float4 bi = *(const float4*)&bias[ch0];
        #pragma unroll
        for (int r = 0; r < 4; r++) {
          const float biv = r == 0 ? bi.x : r == 1 ? bi.y : r == 2 ? bi.z : bi.w;
          of32[((size_t)(bb * TC + ch0 + r)) * TT + tloc] =
              (acc[mi][nj][r] + biv) * mm;
        }
      }
    }
  }
}

// ---------------- banded attention, LDS-staged K/V, d-split x2 ----------------
#define AROWS (128 + 2 * WOVR)   // 146
#define ASTR  36                 // 32 data + 4 pad ushorts = 72B rows
__global__ __launch_bounds__(256) void k_attn_lds(
    const unsigned short* __restrict__ QKV, const float* __restrict__ mf,
    unsigned short* __restrict__ AO) {
  const int t0 = blockIdx.x * 128;
  const int h = blockIdx.y, b = blockIdx.z;
  const int tid = threadIdx.x;
  const int tloc = tid >> 1, half = tid & 1;
  const size_t SZ = (size_t)MTOT * KSZ;
  const unsigned short* Qp = QKV;
  const unsigned short* Kp = QKV + SZ;
  const unsigned short* Vp = QKV + 2 * SZ;
  __shared__ unsigned short Ks[AROWS * ASTR], Vs[AROWS * ASTR];
  __shared__ float mfs[AROWS];

  for (int idx = tid; idx < 2 * AROWS * 4; idx += 256) {
    const int bufv = idx >= AROWS * 4;
    const int ci = idx - bufv * AROWS * 4;
    const int r = ci >> 2, c = ci & 3;
    const int tk = t0 - WOVR + r;
    const int tkc = tk < 0 ? 0 : (tk >= TT ? TT - 1 : tk);
    const unsigned short* src =
        (bufv ? Vp : Kp) + ((size_t)(b * TT + tkc)) * TC + h * TD + c * 8;
    uint4 v = *(const uint4*)src;
    unsigned short* dst = (bufv ? Vs : Ks) + r * ASTR + c * 8;
    uint2 lo; lo.x = v.x; lo.y = v.y;
    uint2 hi; hi.x = v.z; hi.y = v.w;
    *(uint2*)dst = lo; *(uint2*)(dst + 4) = hi;
  }
  if (tid < AROWS) {
    const int tk = t0 - WOVR + tid;
    mfs[tid] = (tk >= 0 && tk < TT) ? (mf[b * TT + tk] != 0.f ? 0.f : -1e4f)
                                    : -1e30f;
  }
  __syncthreads();

  const int t = t0 + tloc;
  const float qm = mf[b * TT + t];
  float q[16];
  {
    const unsigned short* qr = Qp + ((size_t)(b * TT + t)) * TC + h * TD + half * 16;
    #pragma unroll
    for (int c = 0; c < 2; c++) {
      u16x8 v = *(const u16x8*)(qr + c * 8);
      #pragma unroll
      for (int j = 0; j < 8; j++) q[c * 8 + j] = bf2f(v[j]);
    }
  }
  float e[TW];
  float smax = -3.0e38f;
  #pragma unroll
  for (int j = 0; j < TW; j++) {
    const unsigned short* kr = Ks + (tloc + j) * ASTR + half * 16;
    float acc = 0.f;
    #pragma unroll
    for (int c = 0; c < 4; c++) {
      uint2 w = *(const uint2*)(kr + c * 4);
      acc = fmaf(q[c*4+0], bf2f((unsigned short)(w.x & 0xffffu)), acc);
      acc = fmaf(q[c*4+1], bf2f((unsigned short)(w.x >> 16)), acc);
      acc = fmaf(q[c*4+2], bf2f((unsigned short)(w.y & 0xffffu)), acc);
      acc = fmaf(q[c*4+3], bf2f((unsigned short)(w.y >> 16)), acc);
    }
    acc += __shfl_xor(acc, 1, 64);
    const float sv = acc * SCALE + mfs[tloc + j];
    e[j] = sv;
    smax = fmaxf(smax, sv);
  }
  float den = 0.f;
  #pragma unroll
  for (int j = 0; j < TW; j++) { const float ev = __expf(e[j] - smax); e[j] = ev; den += ev; }
  float o[16] = {};
  #pragma unroll
  for (int j = 0; j < TW; j++) {
    const unsigned short* vr = Vs + (tloc + j) * ASTR + half * 16;
    const float p = e[j];
    #pragma unroll
    for (int c = 0; c < 4; c++) {
      uint2 w = *(const uint2*)(vr + c * 4);
      o[c*4+0] = fmaf(p, bf2f((unsigned short)(w.x & 0xffffu)), o[c*4+0]);
      o[c*4+1] = fmaf(p, bf2f((unsigned short)(w.x >> 16)), o[c*4+1]);
      o[c*4+2] = fmaf(p, bf2f((unsigned short)(w.y & 0xffffu)), o[c*4+2]);
      o[c*4+3] = fmaf(p, bf2f((unsigned short)(w.y >> 16)), o[c*4+3]);
    }
  }
  const float sc = qm / den;
  unsigned short tmp[16];
  #pragma unroll
  for (int i = 0; i < 16; i++) tmp[i] = f2bf(o[i] * sc);
  unsigned short* op = AO + ((size_t)(b * TT + t)) * TC + h * TD + half * 16;
  *(u16x8*)(op)     = *(const u16x8*)(tmp);
  *(u16x8*)(op + 8) = *(const u16x8*)(tmp + 8);
}

extern "C" void kernel_launch(void* const* d_in, const int* in_sizes, int n_in,
                              void* d_out, int out_size, void* d_ws, size_t ws_size,
                              hipStream_t stream) {
  const float* x       = (const float*)d_in[0];
  const float* w_qconv = (const float*)d_in[1];
  const float* w_kconv = (const float*)d_in[2];
  const float* w_vconv = (const float*)d_in[3];
  const float* g_q = (const float*)d_in[4];
  const float* b_q = (const float*)d_in[5];
  const float* g_k = (const float*)d_in[6];
  const float* b_k = (const float*)d_in[7];
  const float* g_v = (const float*)d_in[8];
  const float* b_v = (const float*)d_in[9];
  const float* w_query = (const float*)d_in[10];
  const float* b_query = (const float*)d_in[11];
  const float* w_key   = (const float*)d_in[12];
  const float* b_key   = (const float*)d_in[13];
  const float* w_value = (const float*)d_in[14];
  const float* b_value = (const float*)d_in[15];
  const float* w_proj  = (const float*)d_in[16];
  const float* b_proj  = (const float*)d_in[17];
  const unsigned char* mraw = (const unsigned char*)d_in[18];
  float* out = (float*)d_out;

  uint8_t* w8 = (uint8_t*)d_ws;
  float* mf            = (float*)w8;                                   // 36 KB
  unsigned short* Wbf  = (unsigned short*)(w8 + (1ull << 20));         // 2 MB
  unsigned short* Aall = (unsigned short*)(w8 + (4ull << 20));         // 28.3 MB
  unsigned short* QKV  = (unsigned short*)(w8 + (34ull << 20));        // 28.3 MB
  unsigned short* AO   = (unsigned short*)(w8 + (63ull << 20));        // 9.4 MB

  k_conv_ln_t<<<dim3(144, TB), dim3(512), 0, stream>>>(
      x, w_qconv, w_kconv, w_vconv, g_q, b_q, g_k, b_k, g_v, b_v,
      w_query, w_key, w_value, w_proj, mraw, Wbf, mf, out, Aall);
  k_gemm_mfma<0><<<dim3(864), dim3(256), 0, stream>>>(
      Aall, Wbf, b_query, b_key, b_value, QKV, nullptr, mf);
  k_attn_lds<<<dim3(TT / 128, TH, TB), dim3(256), 0, stream>>>(QKV, mf, AO);
  k_gemm_mfma<1><<<dim3(288), dim3(256), 0, stream>>>(
      AO, Wbf + 3 * TC * TC, b_proj, b_proj, b_proj, nullptr, out, mf);
}